// Round 8
// baseline (379.373 us; speedup 1.0000x reference)
//
#include <hip/hip_runtime.h>
#include <hip/hip_fp16.h>

#define HD  64
#define FIN 128

#define NBKT 1568        // dst buckets (dst >> 6), covers N <= 100352
#define EC   4096        // edges per block in sorted edge kernel
#define EW   2048        // LDS dst window per block

// ---- workspace float offsets ----
#define WS_W1T   0
#define WS_MK    8192
#define WS_MQ    12288
#define WS_MVW   16384
#define WS_WSK1  20480
#define WS_BK    20544
#define WS_BQ    20608
#define WS_BVW   20672
#define WS_BASE  20736
#define WS_H1    20800   // [N][64] bf16 h1 (32 floats-equiv/node)
// then: karr [N x 64B u8], srec [N x 192B: q u8|vw f16], sorted int2[E], ghist/gcur

#define C1f  3.9026344e-3f
#define C3f  (-7.67612e-8f)
#define C5f  1.2236660e-12f

__device__ __forceinline__ unsigned bf16rne(float f) {
    unsigned u = __float_as_uint(f);
    unsigned r = ((u >> 16) & 1u) + 0x7fffu;
    return (u + r) >> 16;
}
__device__ __forceinline__ uint2 pack4(float4 v) {
    uint2 r;
    r.x = bf16rne(v.x) | (bf16rne(v.y) << 16);
    r.y = bf16rne(v.z) | (bf16rne(v.w) << 16);
    return r;
}
__device__ __forceinline__ float blo(unsigned u) { return __uint_as_float(u << 16); }
__device__ __forceinline__ float bhi(unsigned u) { return __uint_as_float(u & 0xffff0000u); }

__device__ __forceinline__ unsigned packh2(float a, float b) {
    __half2 h = __floats2half2_rn(a, b);
    return *(unsigned*)&h;
}
__device__ __forceinline__ uint2 packh4(float4 v) {
    uint2 r; r.x = packh2(v.x, v.y); r.y = packh2(v.z, v.w); return r;
}
__device__ __forceinline__ float2 h2f2(unsigned u) {
    __half2 h = *(__half2*)&u;
    return __half22float2(h);
}
__device__ __forceinline__ unsigned encq4(float4 v) {
    int e0 = min(max(__float2int_rn(fmaf(v.x, 64.f, 128.f)), 0), 255);
    int e1 = min(max(__float2int_rn(fmaf(v.y, 64.f, 128.f)), 0), 255);
    int e2 = min(max(__float2int_rn(fmaf(v.z, 64.f, 128.f)), 0), 255);
    int e3 = min(max(__float2int_rn(fmaf(v.w, 64.f, 128.f)), 0), 255);
    return (unsigned)e0 | ((unsigned)e1 << 8) | ((unsigned)e2 << 16) | ((unsigned)e3 << 24);
}
// 4 features: k,q u8 quads + 4 fp16 vw
__device__ __forceinline__ float grp4h(unsigned ku, unsigned qu, unsigned v01,
                                       unsigned v23, float p) {
    float2 va = h2f2(v01), vb = h2f2(v23);
    float vf[4] = { va.x, va.y, vb.x, vb.y };
    #pragma unroll
    for (int i = 0; i < 4; ++i) {
        float kf = (float)((ku >> (8 * i)) & 255u);
        float qf = (float)((qu >> (8 * i)) & 255u);
        float xx = kf + qf;
        xx = fminf(fmaxf(xx, 128.f), 384.f);
        float sv = xx - 256.f;
        float z = sv * sv;
        float w = fmaf(z, C5f, C3f);
        w = fmaf(z, w, C1f);
        p = fmaf(vf[i] * sv, w, p);
        p = fmaf(vf[i], 0.5f, p);
    }
    return p;
}

// ---------------------------------------------------------------------------
__global__ void gnn_zero(unsigned* __restrict__ ghist) {
    int i = blockIdx.x * 256 + threadIdx.x;
    if (i < NBKT) ghist[i] = 0u;
}

// hist: per-block LDS histogram of dst>>6, merged with one atomic/bucket
__global__ __launch_bounds__(256) void gnn_hist(const int* __restrict__ ei,
                                                unsigned* __restrict__ ghist, int E) {
    __shared__ unsigned h[NBKT];
    int tid = threadIdx.x;
    for (int j = tid; j < NBKT; j += 256) h[j] = 0u;
    __syncthreads();
    int chunk = (E + 63) / 64;
    int cs = blockIdx.x * chunk, ce = min(cs + chunk, E);
    for (int e = cs + tid; e < ce; e += 256)
        atomicAdd(&h[(unsigned)ei[E + e] >> 6], 1u);
    __syncthreads();
    for (int j = tid; j < NBKT; j += 256)
        if (h[j]) atomicAdd(&ghist[j], h[j]);
}

// scan: exclusive prefix over NBKT buckets -> gcur
__global__ __launch_bounds__(256) void gnn_scan(const unsigned* __restrict__ ghist,
                                                unsigned* __restrict__ gcur) {
    __shared__ unsigned vals[NBKT];
    __shared__ unsigned part[256];
    int tid = threadIdx.x;
    for (int j = tid; j < NBKT; j += 256) vals[j] = ghist[j];
    __syncthreads();
    unsigned s = 0;
    int j0 = tid * 7;
    for (int j = j0; j < j0 + 7 && j < NBKT; ++j) s += vals[j];
    part[tid] = s;
    __syncthreads();
    if (tid == 0) {
        unsigned run = 0;
        for (int i = 0; i < 256; ++i) { unsigned t = part[i]; part[i] = run; run += t; }
    }
    __syncthreads();
    unsigned run = part[tid];
    for (int j = j0; j < j0 + 7 && j < NBKT; ++j) { gcur[j] = run; run += vals[j]; }
}

// scatter: per-block count + reserve + place.  sorted[pos] = (src,dst)
__global__ __launch_bounds__(256) void gnn_scatter(const int* __restrict__ ei,
                                                   unsigned* __restrict__ gcur,
                                                   int2* __restrict__ sorted, int E) {
    __shared__ unsigned h[NBKT];
    __shared__ unsigned base[NBKT];
    int tid = threadIdx.x;
    for (int j = tid; j < NBKT; j += 256) h[j] = 0u;
    __syncthreads();
    int chunk = (E + 63) / 64;
    int cs = blockIdx.x * chunk, ce = min(cs + chunk, E);
    for (int e = cs + tid; e < ce; e += 256)
        atomicAdd(&h[(unsigned)ei[E + e] >> 6], 1u);
    __syncthreads();
    for (int j = tid; j < NBKT; j += 256) {
        unsigned c = h[j];
        if (c) base[j] = atomicAdd(&gcur[j], c);
        h[j] = 0u;
    }
    __syncthreads();
    for (int e = cs + tid; e < ce; e += 256) {
        int s = ei[e], d = ei[E + e];
        unsigned b = (unsigned)d >> 6;
        unsigned off = atomicAdd(&h[b], 1u);
        sorted[base[b] + off] = make_int2(s, d);
    }
}

// ---------------------------------------------------------------------------
// Prep (14 blocks): W1 transpose + W2-folds + skip fold.  (unchanged)
// ---------------------------------------------------------------------------
__global__ void gnn_prep(const float* __restrict__ W1, const float* __restrict__ W2,
                         const float* __restrict__ b2,
                         const float* __restrict__ Wk, const float* __restrict__ bk,
                         const float* __restrict__ Wq, const float* __restrict__ bq,
                         const float* __restrict__ Wv, const float* __restrict__ bv,
                         const float* __restrict__ Wsm, const float* __restrict__ Wsc,
                         const float* __restrict__ bgate, const float* __restrict__ bsc,
                         float* __restrict__ ws) {
    __shared__ float w2s[4096];
    __shared__ float wxsT[65 * 64];
    int b = blockIdx.x, t = threadIdx.x;
    if (b == 0) {
        for (int idx = t; idx < HD * FIN; idx += blockDim.x) {
            int c = idx / FIN, j = idx % FIN;
            ws[WS_W1T + j * HD + c] = W1[idx];
        }
    } else if (b <= 12) {
        int m = (b - 1) >> 2, qtr = (b - 1) & 3;
        const float* Wx = (m == 0) ? Wk : (m == 1) ? Wq : Wv;
        const float* bx = (m == 0) ? bk : (m == 1) ? bq : bv;
        int moff = (m == 0) ? WS_MK : (m == 1) ? WS_MQ : WS_MVW;
        int boff = (m == 0) ? WS_BK : (m == 1) ? WS_BQ : WS_BVW;
        for (int i = t * 4; i < 4096; i += 1024)
            *(float4*)&w2s[i] = *(const float4*)&W2[i];
        for (int idx = t; idx < 4096; idx += 256) {
            int o = idx >> 6, c = idx & 63;
            wxsT[c * 65 + o] = Wx[idx];
        }
        __syncthreads();
        for (int idx = t; idx < 1024; idx += 256) {
            int a = qtr * 16 + (idx >> 6), o = idx & 63;
            float acc = 0.f;
            for (int c = 0; c < HD; ++c) acc += w2s[c * HD + a] * wxsT[c * 65 + o];
            if (m == 2) acc *= Wsc[o];
            ws[moff + a * HD + o] = acc;
        }
        if (qtr == 0 && t < HD) {
            float acc = bx[t];
            for (int c = 0; c < HD; ++c) acc += b2[c] * wxsT[c * 65 + t];
            if (m == 2) acc *= Wsc[t];
            ws[boff + t] = acc;
        }
    } else {
        __shared__ float wsk[HD];
        if (t < HD) {
            float a = 0.f;
            for (int d = 0; d < HD; ++d) a += Wsm[d * HD + t] * Wsc[d];
            wsk[t] = a;
        }
        __syncthreads();
        if (t < HD) {
            float a = 0.f;
            for (int c = 0; c < HD; ++c) a += W2[c * HD + t] * wsk[c];
            ws[WS_WSK1 + t] = a;
        }
        if (t == 0) {
            float a = bsc[0];
            for (int d = 0; d < HD; ++d) a += bgate[d] * Wsc[d];
            for (int c = 0; c < HD; ++c) a += b2[c] * wsk[c];
            ws[WS_BASE] = a;
        }
    }
}

// ---------------------------------------------------------------------------
// h1 = relu(x @ W1T + b1), bf16 out.  (R7/R4 form, unchanged)
// ---------------------------------------------------------------------------
__global__ __launch_bounds__(256, 2) void gnn_mlp1(const float* __restrict__ x,
                                                   const float* __restrict__ b1,
                                                   const float* __restrict__ ws,
                                                   uint2* __restrict__ h1out, int N) {
    __shared__ float w[FIN * HD + HD];
    __shared__ float xs[64 * 132];
    int tid = threadIdx.x;
    for (int i = tid * 4; i < FIN * HD; i += 1024)
        *(float4*)&w[i] = *(const float4*)&ws[WS_W1T + i];
    if (tid < HD) w[FIN * HD + tid] = b1[tid];

    int nbase = blockIdx.x * 64;
    for (int i4 = tid; i4 < 2048; i4 += 256) {
        int nl = i4 >> 5, c4 = i4 & 31;
        int node = min(nbase + nl, N - 1);
        float4 xv = ((const float4*)x)[(size_t)node * 32 + c4];
        *(float4*)&xs[nl * 132 + c4 * 4] = xv;
    }
    __syncthreads();

    int wv = tid >> 6, l = tid & 63, g = l >> 4, f = l & 15;
    int nl0 = wv * 16 + g * 4;

    float4 bias = *(const float4*)&w[FIN * HD + 4 * f];
    float4 acc[4];
    #pragma unroll
    for (int n = 0; n < 4; ++n) acc[n] = bias;

    for (int j = 0; j < FIN; j += 4) {
        float4 xv[4];
        #pragma unroll
        for (int n = 0; n < 4; ++n) xv[n] = *(const float4*)&xs[(nl0 + n) * 132 + j];
        #pragma unroll
        for (int jj = 0; jj < 4; ++jj) {
            float4 wvv = *(const float4*)&w[(j + jj) * HD + 4 * f];
            #pragma unroll
            for (int n = 0; n < 4; ++n) {
                float xsc = ((const float*)&xv[n])[jj];
                acc[n].x += xsc * wvv.x; acc[n].y += xsc * wvv.y;
                acc[n].z += xsc * wvv.z; acc[n].w += xsc * wvv.w;
            }
        }
    }
    #pragma unroll
    for (int n = 0; n < 4; ++n) {
        int node = nbase + nl0 + n;
        if (node < N) {
            float4 r;
            r.x = fmaxf(acc[n].x, 0.f); r.y = fmaxf(acc[n].y, 0.f);
            r.z = fmaxf(acc[n].z, 0.f); r.w = fmaxf(acc[n].w, 0.f);
            h1out[(size_t)node * 16 + f] = pack4(r);
        }
    }
}

// ---------------------------------------------------------------------------
// Fused k/q/vw/score.  karr u8[N][64]; srec [N][192B] = q u8[64] | vw f16[64].
// ---------------------------------------------------------------------------
__global__ __launch_bounds__(256, 2) void gnn_kqvs(const float* __restrict__ ws,
                                                   const uint2* __restrict__ h1,
                                                   unsigned* __restrict__ karr,
                                                   unsigned* __restrict__ srec,
                                                   float* __restrict__ score, int N) {
    __shared__ float w[12544];
    __shared__ unsigned hs[64 * 36];
    const int L_MK = 0, L_MQ = 4096, L_MVW = 8192, L_WSK = 12288,
              L_BK = 12352, L_BQ = 12416, L_BVW = 12480;
    int tid = threadIdx.x;
    for (int i = tid * 4; i < 12544; i += 1024)
        *(float4*)&w[i] = *(const float4*)&ws[WS_MK + i];

    int nbase = blockIdx.x * 64;
    for (int i4 = tid; i4 < 512; i4 += 256) {
        int nl = i4 >> 3, c4 = i4 & 7;
        int node = min(nbase + nl, N - 1);
        uint4 hv = ((const uint4*)h1)[(size_t)node * 8 + c4];
        *(uint4*)&hs[nl * 36 + c4 * 4] = hv;
    }
    __syncthreads();
    float base = ws[WS_BASE];

    int wv = tid >> 6, l = tid & 63, g = l >> 4, f = l & 15;
    int nl0 = wv * 16 + g * 4;

    float4 accK[4], accQ[4], accV[4];
    float sacc[4];
    float4 bK = *(const float4*)&w[L_BK + 4 * f];
    float4 bQ = *(const float4*)&w[L_BQ + 4 * f];
    float4 bV = *(const float4*)&w[L_BVW + 4 * f];
    #pragma unroll
    for (int n = 0; n < 4; ++n) { accK[n] = bK; accQ[n] = bQ; accV[n] = bV; sacc[n] = 0.f; }

    for (int a = 0; a < HD; a += 4) {
        float hf[4][4];
        #pragma unroll
        for (int n = 0; n < 4; ++n) {
            uint2 hu = *(const uint2*)&hs[(nl0 + n) * 36 + (a >> 1)];
            hf[n][0] = blo(hu.x); hf[n][1] = bhi(hu.x);
            hf[n][2] = blo(hu.y); hf[n][3] = bhi(hu.y);
        }
        #pragma unroll
        for (int aa = 0; aa < 4; ++aa) {
            float4 mk = *(const float4*)&w[L_MK + (a + aa) * HD + 4 * f];
            float4 mq = *(const float4*)&w[L_MQ + (a + aa) * HD + 4 * f];
            float4 mv = *(const float4*)&w[L_MVW + (a + aa) * HD + 4 * f];
            float wk = w[L_WSK + a + aa];
            #pragma unroll
            for (int n = 0; n < 4; ++n) {
                float s1 = hf[n][aa];
                accK[n].x += s1 * mk.x; accK[n].y += s1 * mk.y;
                accK[n].z += s1 * mk.z; accK[n].w += s1 * mk.w;
                accQ[n].x += s1 * mq.x; accQ[n].y += s1 * mq.y;
                accQ[n].z += s1 * mq.z; accQ[n].w += s1 * mq.w;
                accV[n].x += s1 * mv.x; accV[n].y += s1 * mv.y;
                accV[n].z += s1 * mv.z; accV[n].w += s1 * mv.w;
                sacc[n] += s1 * wk;
            }
        }
    }
    #pragma unroll
    for (int n = 0; n < 4; ++n) {
        int node = nbase + nl0 + n;
        if (node < N) {
            karr[(size_t)node * 16 + f] = encq4(accK[n]);
            unsigned* sr = srec + (size_t)node * 48;
            sr[f] = encq4(accQ[n]);
            *(uint2*)&sr[16 + 2 * f] = packh4(accV[n]);
            if (f == 0) score[node] = base + sacc[n];
        }
    }
}

// ---------------------------------------------------------------------------
// Edge over dst-sorted list: LDS score window, k amortized via dst-runs,
// ~one global atomic per touched dst per block (+fallback for out-of-window).
// ---------------------------------------------------------------------------
__global__ __launch_bounds__(256) void gnn_edge_sorted(const int2* __restrict__ sorted,
                                                       const uint4* __restrict__ karr,
                                                       const uint4* __restrict__ srec,
                                                       float* __restrict__ score,
                                                       int E, int N) {
    __shared__ float sc[EW];
    int start = blockIdx.x * EC;
    if (start >= E) return;
    int tid = threadIdx.x;
    int2 first = sorted[start];
    int wlo = (first.y >> 6) << 6;
    for (int j = tid; j < EW; j += 256) sc[j] = 0.f;
    __syncthreads();

    int g = tid >> 2, f = tid & 3;
    for (int ii = 0; ii < 32; ++ii) {
        int ea = start + g + (ii * 2) * 64;
        int eb = ea + 64;
        bool va_ok = ea < E, vb_ok = eb < E;
        int2 eda = va_ok ? sorted[ea] : make_int2(0, 0);
        int2 edb = vb_ok ? sorted[eb] : make_int2(0, 0);
        uint4 ku0 = karr[(size_t)eda.y * 4 + f];
        uint4 qu0 = srec[(size_t)eda.x * 12 + f];
        uint4 va0 = srec[(size_t)eda.x * 12 + 4 + 2 * f];
        uint4 vb0 = srec[(size_t)eda.x * 12 + 5 + 2 * f];
        uint4 ku1 = karr[(size_t)edb.y * 4 + f];
        uint4 qu1 = srec[(size_t)edb.x * 12 + f];
        uint4 va1 = srec[(size_t)edb.x * 12 + 4 + 2 * f];
        uint4 vb1 = srec[(size_t)edb.x * 12 + 5 + 2 * f];
        float p0 = 0.f, p1 = 0.f;
        p0 = grp4h(ku0.x, qu0.x, va0.x, va0.y, p0);
        p0 = grp4h(ku0.y, qu0.y, va0.z, va0.w, p0);
        p0 = grp4h(ku0.z, qu0.z, vb0.x, vb0.y, p0);
        p0 = grp4h(ku0.w, qu0.w, vb0.z, vb0.w, p0);
        p1 = grp4h(ku1.x, qu1.x, va1.x, va1.y, p1);
        p1 = grp4h(ku1.y, qu1.y, va1.z, va1.w, p1);
        p1 = grp4h(ku1.z, qu1.z, vb1.x, vb1.y, p1);
        p1 = grp4h(ku1.w, qu1.w, vb1.z, vb1.w, p1);
        p0 += __shfl_down(p0, 2, 4);
        p0 += __shfl_down(p0, 1, 4);
        p1 += __shfl_down(p1, 2, 4);
        p1 += __shfl_down(p1, 1, 4);
        if (f == 0) {
            if (va_ok) {
                int w0 = eda.y - wlo;
                if ((unsigned)w0 < EW) atomicAdd(&sc[w0], p0);
                else atomicAdd(&score[eda.y], p0);
            }
            if (vb_ok) {
                int w1 = edb.y - wlo;
                if ((unsigned)w1 < EW) atomicAdd(&sc[w1], p1);
                else atomicAdd(&score[edb.y], p1);
            }
        }
    }
    __syncthreads();
    for (int j = tid; j < EW; j += 256) {
        float v = sc[j];
        int node = wlo + j;
        if (v != 0.f && node < N) atomicAdd(&score[node], v);
    }
}

// ---------------------------------------------------------------------------
extern "C" void kernel_launch(void* const* d_in, const int* in_sizes, int n_in,
                              void* d_out, int out_size, void* d_ws, size_t ws_size,
                              hipStream_t stream) {
    const float* x    = (const float*)d_in[0];
    const int*   ei   = (const int*)d_in[1];
    const float* W1   = (const float*)d_in[2];
    const float* b1   = (const float*)d_in[3];
    const float* W2   = (const float*)d_in[4];
    const float* b2   = (const float*)d_in[5];
    const float* Wk   = (const float*)d_in[6];
    const float* bk   = (const float*)d_in[7];
    const float* Wq   = (const float*)d_in[8];
    const float* bq   = (const float*)d_in[9];
    const float* Wv   = (const float*)d_in[10];
    const float* bv   = (const float*)d_in[11];
    const float* Wsm  = (const float*)d_in[12];
    const float* bgat = (const float*)d_in[13];
    const float* Wsc  = (const float*)d_in[14];
    const float* bsc  = (const float*)d_in[15];

    int N = in_sizes[0] / FIN;
    int E = in_sizes[1] / 2;

    float* ws    = (float*)d_ws;
    float* h1    = ws + WS_H1;                    // N*32 floats (bf16 h1)
    float* karr  = h1 + (size_t)N * 32;           // N*16 u32
    float* srec  = karr + (size_t)N * 16;         // N*48 u32
    float* sortf = srec + (size_t)N * 48;         // E int2 = 2E ints
    unsigned* ghist = (unsigned*)(sortf + (size_t)E * 2);
    unsigned* gcur  = ghist + NBKT;
    int2* sorted = (int2*)sortf;
    float* score = (float*)d_out;

    int NB = (N + 63) / 64;
    int NBE = (E + EC - 1) / EC;
    gnn_zero<<<(NBKT + 255) / 256, 256, 0, stream>>>(ghist);
    gnn_prep<<<14, 256, 0, stream>>>(W1, W2, b2, Wk, bk, Wq, bq, Wv, bv,
                                     Wsm, Wsc, bgat, bsc, ws);
    gnn_hist<<<64, 256, 0, stream>>>(ei, ghist, E);
    gnn_scan<<<1, 256, 0, stream>>>(ghist, gcur);
    gnn_scatter<<<64, 256, 0, stream>>>(ei, gcur, sorted, E);
    gnn_mlp1<<<NB, 256, 0, stream>>>(x, b1, ws, (uint2*)h1, N);
    gnn_kqvs<<<NB, 256, 0, stream>>>(ws, (const uint2*)h1, (unsigned*)karr,
                                     (unsigned*)srec, score, N);
    gnn_edge_sorted<<<NBE, 256, 0, stream>>>(sorted, (const uint4*)karr,
                                             (const uint4*)srec, score, E, N);
}

// Round 9
// 329.011 us; speedup vs baseline: 1.1531x; 1.1531x over previous
//
#include <hip/hip_runtime.h>
#include <hip/hip_fp16.h>

#define HD  64
#define FIN 128

#define BG_SH    10      // bucket = dst >> 10 (1024 nodes/bucket)
#define NBKT_MAX 128     // covers N <= 131072
#define EC   2048        // edges per block in sorted edge kernel
#define EW   2048        // LDS dst window per block (2 buckets)

// ---- workspace float offsets ----
#define WS_W1T   0
#define WS_MK    8192
#define WS_MQ    12288
#define WS_MVW   16384
#define WS_WSK1  20480
#define WS_BK    20544
#define WS_BQ    20608
#define WS_BVW   20672
#define WS_BASE  20736
#define WS_H1    20800   // [N][64] bf16 h1 (32 floats-equiv/node)
// then: karr [N x 64B u8], srec [N x 192B: q u8|vw f16], sorted int2[E], ghist/gcur

#define C1f  3.9026344e-3f
#define C3f  (-7.67612e-8f)
#define C5f  1.2236660e-12f

__device__ __forceinline__ unsigned bf16rne(float f) {
    unsigned u = __float_as_uint(f);
    unsigned r = ((u >> 16) & 1u) + 0x7fffu;
    return (u + r) >> 16;
}
__device__ __forceinline__ uint2 pack4(float4 v) {
    uint2 r;
    r.x = bf16rne(v.x) | (bf16rne(v.y) << 16);
    r.y = bf16rne(v.z) | (bf16rne(v.w) << 16);
    return r;
}
__device__ __forceinline__ float blo(unsigned u) { return __uint_as_float(u << 16); }
__device__ __forceinline__ float bhi(unsigned u) { return __uint_as_float(u & 0xffff0000u); }

__device__ __forceinline__ unsigned packh2(float a, float b) {
    __half2 h = __floats2half2_rn(a, b);
    return *(unsigned*)&h;
}
__device__ __forceinline__ uint2 packh4(float4 v) {
    uint2 r; r.x = packh2(v.x, v.y); r.y = packh2(v.z, v.w); return r;
}
__device__ __forceinline__ float2 h2f2(unsigned u) {
    __half2 h = *(__half2*)&u;
    return __half22float2(h);
}
__device__ __forceinline__ unsigned encq4(float4 v) {
    int e0 = min(max(__float2int_rn(fmaf(v.x, 64.f, 128.f)), 0), 255);
    int e1 = min(max(__float2int_rn(fmaf(v.y, 64.f, 128.f)), 0), 255);
    int e2 = min(max(__float2int_rn(fmaf(v.z, 64.f, 128.f)), 0), 255);
    int e3 = min(max(__float2int_rn(fmaf(v.w, 64.f, 128.f)), 0), 255);
    return (unsigned)e0 | ((unsigned)e1 << 8) | ((unsigned)e2 << 16) | ((unsigned)e3 << 24);
}
// 4 features: k,q u8 quads + 4 fp16 vw
__device__ __forceinline__ float grp4h(unsigned ku, unsigned qu, unsigned v01,
                                       unsigned v23, float p) {
    float2 va = h2f2(v01), vb = h2f2(v23);
    float vf[4] = { va.x, va.y, vb.x, vb.y };
    #pragma unroll
    for (int i = 0; i < 4; ++i) {
        float kf = (float)((ku >> (8 * i)) & 255u);
        float qf = (float)((qu >> (8 * i)) & 255u);
        float xx = kf + qf;
        xx = fminf(fmaxf(xx, 128.f), 384.f);
        float sv = xx - 256.f;
        float z = sv * sv;
        float w = fmaf(z, C5f, C3f);
        w = fmaf(z, w, C1f);
        p = fmaf(vf[i] * sv, w, p);
        p = fmaf(vf[i], 0.5f, p);
    }
    return p;
}

// ---------------------------------------------------------------------------
__global__ void gnn_zero(unsigned* __restrict__ ghist, int nbkt) {
    int i = threadIdx.x;
    if (i < nbkt) ghist[i] = 0u;
}

// hist: 256 blocks, int4 dst reads, 98-counter LDS hist, one atomic/bucket
__global__ __launch_bounds__(256) void gnn_hist(const int* __restrict__ ei,
                                                unsigned* __restrict__ ghist,
                                                int E, int nbkt, int c4) {
    __shared__ unsigned h[NBKT_MAX];
    int tid = threadIdx.x;
    if (tid < nbkt) h[tid] = 0u;
    __syncthreads();
    const int4* dst4 = (const int4*)(ei + E);
    int nE4 = E >> 2;
    int s4 = blockIdx.x * c4, e4 = min(s4 + c4, nE4);
    for (int i = s4 + tid; i < e4; i += 256) {
        int4 d = dst4[i];
        atomicAdd(&h[(unsigned)d.x >> BG_SH], 1u);
        atomicAdd(&h[(unsigned)d.y >> BG_SH], 1u);
        atomicAdd(&h[(unsigned)d.z >> BG_SH], 1u);
        atomicAdd(&h[(unsigned)d.w >> BG_SH], 1u);
    }
    if (blockIdx.x == 0)
        for (int e = (E & ~3) + tid; e < E; e += 256)
            atomicAdd(&h[(unsigned)ei[E + e] >> BG_SH], 1u);
    __syncthreads();
    if (tid < nbkt && h[tid]) atomicAdd(&ghist[tid], h[tid]);
}

// scan: 98 buckets, LDS-staged serial scan
__global__ void gnn_scan(const unsigned* __restrict__ ghist,
                         unsigned* __restrict__ gcur, int nbkt) {
    __shared__ unsigned v[NBKT_MAX];
    int tid = threadIdx.x;
    if (tid < nbkt) v[tid] = ghist[tid];
    __syncthreads();
    if (tid == 0) {
        unsigned run = 0;
        for (int j = 0; j < nbkt; ++j) { unsigned t = v[j]; v[j] = run; run += t; }
    }
    __syncthreads();
    if (tid < nbkt) gcur[tid] = v[tid];
}

// scatter: 256 blocks, count + reserve + place (int4 reads, int2 writes)
__global__ __launch_bounds__(256) void gnn_scatter(const int* __restrict__ ei,
                                                   unsigned* __restrict__ gcur,
                                                   int2* __restrict__ sorted,
                                                   int E, int nbkt, int c4) {
    __shared__ unsigned h[NBKT_MAX];
    __shared__ unsigned base[NBKT_MAX];
    int tid = threadIdx.x;
    if (tid < nbkt) h[tid] = 0u;
    __syncthreads();
    const int4* src4 = (const int4*)ei;
    const int4* dst4 = (const int4*)(ei + E);
    int nE4 = E >> 2;
    int s4 = blockIdx.x * c4, e4 = min(s4 + c4, nE4);
    bool tail = (blockIdx.x == 0);
    for (int i = s4 + tid; i < e4; i += 256) {
        int4 d = dst4[i];
        atomicAdd(&h[(unsigned)d.x >> BG_SH], 1u);
        atomicAdd(&h[(unsigned)d.y >> BG_SH], 1u);
        atomicAdd(&h[(unsigned)d.z >> BG_SH], 1u);
        atomicAdd(&h[(unsigned)d.w >> BG_SH], 1u);
    }
    if (tail)
        for (int e = (E & ~3) + tid; e < E; e += 256)
            atomicAdd(&h[(unsigned)ei[E + e] >> BG_SH], 1u);
    __syncthreads();
    if (tid < nbkt) {
        unsigned c = h[tid];
        base[tid] = c ? atomicAdd(&gcur[tid], c) : 0u;
        h[tid] = 0u;
    }
    __syncthreads();
    for (int i = s4 + tid; i < e4; i += 256) {
        int4 s = src4[i];
        int4 d = dst4[i];
        unsigned b0 = (unsigned)d.x >> BG_SH;
        sorted[base[b0] + atomicAdd(&h[b0], 1u)] = make_int2(s.x, d.x);
        unsigned b1 = (unsigned)d.y >> BG_SH;
        sorted[base[b1] + atomicAdd(&h[b1], 1u)] = make_int2(s.y, d.y);
        unsigned b2 = (unsigned)d.z >> BG_SH;
        sorted[base[b2] + atomicAdd(&h[b2], 1u)] = make_int2(s.z, d.z);
        unsigned b3 = (unsigned)d.w >> BG_SH;
        sorted[base[b3] + atomicAdd(&h[b3], 1u)] = make_int2(s.w, d.w);
    }
    if (tail)
        for (int e = (E & ~3) + tid; e < E; e += 256) {
            int s = ei[e], d = ei[E + e];
            unsigned b = (unsigned)d >> BG_SH;
            sorted[base[b] + atomicAdd(&h[b], 1u)] = make_int2(s, d);
        }
}

// ---------------------------------------------------------------------------
// Prep (14 blocks): W1 transpose + W2-folds + skip fold.  (unchanged)
// ---------------------------------------------------------------------------
__global__ void gnn_prep(const float* __restrict__ W1, const float* __restrict__ W2,
                         const float* __restrict__ b2,
                         const float* __restrict__ Wk, const float* __restrict__ bk,
                         const float* __restrict__ Wq, const float* __restrict__ bq,
                         const float* __restrict__ Wv, const float* __restrict__ bv,
                         const float* __restrict__ Wsm, const float* __restrict__ Wsc,
                         const float* __restrict__ bgate, const float* __restrict__ bsc,
                         float* __restrict__ ws) {
    __shared__ float w2s[4096];
    __shared__ float wxsT[65 * 64];
    int b = blockIdx.x, t = threadIdx.x;
    if (b == 0) {
        for (int idx = t; idx < HD * FIN; idx += blockDim.x) {
            int c = idx / FIN, j = idx % FIN;
            ws[WS_W1T + j * HD + c] = W1[idx];
        }
    } else if (b <= 12) {
        int m = (b - 1) >> 2, qtr = (b - 1) & 3;
        const float* Wx = (m == 0) ? Wk : (m == 1) ? Wq : Wv;
        const float* bx = (m == 0) ? bk : (m == 1) ? bq : bv;
        int moff = (m == 0) ? WS_MK : (m == 1) ? WS_MQ : WS_MVW;
        int boff = (m == 0) ? WS_BK : (m == 1) ? WS_BQ : WS_BVW;
        for (int i = t * 4; i < 4096; i += 1024)
            *(float4*)&w2s[i] = *(const float4*)&W2[i];
        for (int idx = t; idx < 4096; idx += 256) {
            int o = idx >> 6, c = idx & 63;
            wxsT[c * 65 + o] = Wx[idx];
        }
        __syncthreads();
        for (int idx = t; idx < 1024; idx += 256) {
            int a = qtr * 16 + (idx >> 6), o = idx & 63;
            float acc = 0.f;
            for (int c = 0; c < HD; ++c) acc += w2s[c * HD + a] * wxsT[c * 65 + o];
            if (m == 2) acc *= Wsc[o];
            ws[moff + a * HD + o] = acc;
        }
        if (qtr == 0 && t < HD) {
            float acc = bx[t];
            for (int c = 0; c < HD; ++c) acc += b2[c] * wxsT[c * 65 + t];
            if (m == 2) acc *= Wsc[t];
            ws[boff + t] = acc;
        }
    } else {
        __shared__ float wsk[HD];
        if (t < HD) {
            float a = 0.f;
            for (int d = 0; d < HD; ++d) a += Wsm[d * HD + t] * Wsc[d];
            wsk[t] = a;
        }
        __syncthreads();
        if (t < HD) {
            float a = 0.f;
            for (int c = 0; c < HD; ++c) a += W2[c * HD + t] * wsk[c];
            ws[WS_WSK1 + t] = a;
        }
        if (t == 0) {
            float a = bsc[0];
            for (int d = 0; d < HD; ++d) a += bgate[d] * Wsc[d];
            for (int c = 0; c < HD; ++c) a += b2[c] * wsk[c];
            ws[WS_BASE] = a;
        }
    }
}

// ---------------------------------------------------------------------------
// h1 = relu(x @ W1T + b1), bf16 out.  (unchanged)
// ---------------------------------------------------------------------------
__global__ __launch_bounds__(256, 2) void gnn_mlp1(const float* __restrict__ x,
                                                   const float* __restrict__ b1,
                                                   const float* __restrict__ ws,
                                                   uint2* __restrict__ h1out, int N) {
    __shared__ float w[FIN * HD + HD];
    __shared__ float xs[64 * 132];
    int tid = threadIdx.x;
    for (int i = tid * 4; i < FIN * HD; i += 1024)
        *(float4*)&w[i] = *(const float4*)&ws[WS_W1T + i];
    if (tid < HD) w[FIN * HD + tid] = b1[tid];

    int nbase = blockIdx.x * 64;
    for (int i4 = tid; i4 < 2048; i4 += 256) {
        int nl = i4 >> 5, c4 = i4 & 31;
        int node = min(nbase + nl, N - 1);
        float4 xv = ((const float4*)x)[(size_t)node * 32 + c4];
        *(float4*)&xs[nl * 132 + c4 * 4] = xv;
    }
    __syncthreads();

    int wv = tid >> 6, l = tid & 63, g = l >> 4, f = l & 15;
    int nl0 = wv * 16 + g * 4;

    float4 bias = *(const float4*)&w[FIN * HD + 4 * f];
    float4 acc[4];
    #pragma unroll
    for (int n = 0; n < 4; ++n) acc[n] = bias;

    for (int j = 0; j < FIN; j += 4) {
        float4 xv[4];
        #pragma unroll
        for (int n = 0; n < 4; ++n) xv[n] = *(const float4*)&xs[(nl0 + n) * 132 + j];
        #pragma unroll
        for (int jj = 0; jj < 4; ++jj) {
            float4 wvv = *(const float4*)&w[(j + jj) * HD + 4 * f];
            #pragma unroll
            for (int n = 0; n < 4; ++n) {
                float xsc = ((const float*)&xv[n])[jj];
                acc[n].x += xsc * wvv.x; acc[n].y += xsc * wvv.y;
                acc[n].z += xsc * wvv.z; acc[n].w += xsc * wvv.w;
            }
        }
    }
    #pragma unroll
    for (int n = 0; n < 4; ++n) {
        int node = nbase + nl0 + n;
        if (node < N) {
            float4 r;
            r.x = fmaxf(acc[n].x, 0.f); r.y = fmaxf(acc[n].y, 0.f);
            r.z = fmaxf(acc[n].z, 0.f); r.w = fmaxf(acc[n].w, 0.f);
            h1out[(size_t)node * 16 + f] = pack4(r);
        }
    }
}

// ---------------------------------------------------------------------------
// Fused k/q/vw/score.  karr u8[N][64]; srec [N][192B] = q u8[64] | vw f16[64].
// (unchanged)
// ---------------------------------------------------------------------------
__global__ __launch_bounds__(256, 2) void gnn_kqvs(const float* __restrict__ ws,
                                                   const uint2* __restrict__ h1,
                                                   unsigned* __restrict__ karr,
                                                   unsigned* __restrict__ srec,
                                                   float* __restrict__ score, int N) {
    __shared__ float w[12544];
    __shared__ unsigned hs[64 * 36];
    const int L_MK = 0, L_MQ = 4096, L_MVW = 8192, L_WSK = 12288,
              L_BK = 12352, L_BQ = 12416, L_BVW = 12480;
    int tid = threadIdx.x;
    for (int i = tid * 4; i < 12544; i += 1024)
        *(float4*)&w[i] = *(const float4*)&ws[WS_MK + i];

    int nbase = blockIdx.x * 64;
    for (int i4 = tid; i4 < 512; i4 += 256) {
        int nl = i4 >> 3, c4 = i4 & 7;
        int node = min(nbase + nl, N - 1);
        uint4 hv = ((const uint4*)h1)[(size_t)node * 8 + c4];
        *(uint4*)&hs[nl * 36 + c4 * 4] = hv;
    }
    __syncthreads();
    float base = ws[WS_BASE];

    int wv = tid >> 6, l = tid & 63, g = l >> 4, f = l & 15;
    int nl0 = wv * 16 + g * 4;

    float4 accK[4], accQ[4], accV[4];
    float sacc[4];
    float4 bK = *(const float4*)&w[L_BK + 4 * f];
    float4 bQ = *(const float4*)&w[L_BQ + 4 * f];
    float4 bV = *(const float4*)&w[L_BVW + 4 * f];
    #pragma unroll
    for (int n = 0; n < 4; ++n) { accK[n] = bK; accQ[n] = bQ; accV[n] = bV; sacc[n] = 0.f; }

    for (int a = 0; a < HD; a += 4) {
        float hf[4][4];
        #pragma unroll
        for (int n = 0; n < 4; ++n) {
            uint2 hu = *(const uint2*)&hs[(nl0 + n) * 36 + (a >> 1)];
            hf[n][0] = blo(hu.x); hf[n][1] = bhi(hu.x);
            hf[n][2] = blo(hu.y); hf[n][3] = bhi(hu.y);
        }
        #pragma unroll
        for (int aa = 0; aa < 4; ++aa) {
            float4 mk = *(const float4*)&w[L_MK + (a + aa) * HD + 4 * f];
            float4 mq = *(const float4*)&w[L_MQ + (a + aa) * HD + 4 * f];
            float4 mv = *(const float4*)&w[L_MVW + (a + aa) * HD + 4 * f];
            float wk = w[L_WSK + a + aa];
            #pragma unroll
            for (int n = 0; n < 4; ++n) {
                float s1 = hf[n][aa];
                accK[n].x += s1 * mk.x; accK[n].y += s1 * mk.y;
                accK[n].z += s1 * mk.z; accK[n].w += s1 * mk.w;
                accQ[n].x += s1 * mq.x; accQ[n].y += s1 * mq.y;
                accQ[n].z += s1 * mq.z; accQ[n].w += s1 * mq.w;
                accV[n].x += s1 * mv.x; accV[n].y += s1 * mv.y;
                accV[n].z += s1 * mv.z; accV[n].w += s1 * mv.w;
                sacc[n] += s1 * wk;
            }
        }
    }
    #pragma unroll
    for (int n = 0; n < 4; ++n) {
        int node = nbase + nl0 + n;
        if (node < N) {
            karr[(size_t)node * 16 + f] = encq4(accK[n]);
            unsigned* sr = srec + (size_t)node * 48;
            sr[f] = encq4(accQ[n]);
            *(uint2*)&sr[16 + 2 * f] = packh4(accV[n]);
            if (f == 0) score[node] = base + sacc[n];
        }
    }
}

// ---------------------------------------------------------------------------
// Edge over dst-sorted list (bucket granularity 1024): LDS score window
// covers 2 buckets; one global atomic per touched dst per block.
// EC=2048 -> 782 blocks (~12 waves/CU).
// ---------------------------------------------------------------------------
__global__ __launch_bounds__(256) void gnn_edge_sorted(const int2* __restrict__ sorted,
                                                       const uint4* __restrict__ karr,
                                                       const uint4* __restrict__ srec,
                                                       float* __restrict__ score,
                                                       int E, int N) {
    __shared__ float sc[EW];
    int start = blockIdx.x * EC;
    if (start >= E) return;
    int tid = threadIdx.x;
    int2 first = sorted[start];
    int wlo = ((unsigned)first.y >> BG_SH) << BG_SH;
    for (int j = tid; j < EW; j += 256) sc[j] = 0.f;
    __syncthreads();

    int g = tid >> 2, f = tid & 3;
    for (int ii = 0; ii < 16; ++ii) {
        int ea = start + g + (ii * 2) * 64;
        int eb = ea + 64;
        bool va_ok = ea < E, vb_ok = eb < E;
        int2 eda = va_ok ? sorted[ea] : make_int2(0, 0);
        int2 edb = vb_ok ? sorted[eb] : make_int2(0, 0);
        uint4 ku0 = karr[(size_t)eda.y * 4 + f];
        uint4 qu0 = srec[(size_t)eda.x * 12 + f];
        uint4 va0 = srec[(size_t)eda.x * 12 + 4 + 2 * f];
        uint4 vb0 = srec[(size_t)eda.x * 12 + 5 + 2 * f];
        uint4 ku1 = karr[(size_t)edb.y * 4 + f];
        uint4 qu1 = srec[(size_t)edb.x * 12 + f];
        uint4 va1 = srec[(size_t)edb.x * 12 + 4 + 2 * f];
        uint4 vb1 = srec[(size_t)edb.x * 12 + 5 + 2 * f];
        float p0 = 0.f, p1 = 0.f;
        p0 = grp4h(ku0.x, qu0.x, va0.x, va0.y, p0);
        p0 = grp4h(ku0.y, qu0.y, va0.z, va0.w, p0);
        p0 = grp4h(ku0.z, qu0.z, vb0.x, vb0.y, p0);
        p0 = grp4h(ku0.w, qu0.w, vb0.z, vb0.w, p0);
        p1 = grp4h(ku1.x, qu1.x, va1.x, va1.y, p1);
        p1 = grp4h(ku1.y, qu1.y, va1.z, va1.w, p1);
        p1 = grp4h(ku1.z, qu1.z, vb1.x, vb1.y, p1);
        p1 = grp4h(ku1.w, qu1.w, vb1.z, vb1.w, p1);
        p0 += __shfl_down(p0, 2, 4);
        p0 += __shfl_down(p0, 1, 4);
        p1 += __shfl_down(p1, 2, 4);
        p1 += __shfl_down(p1, 1, 4);
        if (f == 0) {
            if (va_ok) {
                int w0 = eda.y - wlo;
                if ((unsigned)w0 < EW) atomicAdd(&sc[w0], p0);
                else atomicAdd(&score[eda.y], p0);
            }
            if (vb_ok) {
                int w1 = edb.y - wlo;
                if ((unsigned)w1 < EW) atomicAdd(&sc[w1], p1);
                else atomicAdd(&score[edb.y], p1);
            }
        }
    }
    __syncthreads();
    for (int j = tid; j < EW; j += 256) {
        float v = sc[j];
        int node = wlo + j;
        if (v != 0.f && node < N) atomicAdd(&score[node], v);
    }
}

// ---------------------------------------------------------------------------
extern "C" void kernel_launch(void* const* d_in, const int* in_sizes, int n_in,
                              void* d_out, int out_size, void* d_ws, size_t ws_size,
                              hipStream_t stream) {
    const float* x    = (const float*)d_in[0];
    const int*   ei   = (const int*)d_in[1];
    const float* W1   = (const float*)d_in[2];
    const float* b1   = (const float*)d_in[3];
    const float* W2   = (const float*)d_in[4];
    const float* b2   = (const float*)d_in[5];
    const float* Wk   = (const float*)d_in[6];
    const float* bk   = (const float*)d_in[7];
    const float* Wq   = (const float*)d_in[8];
    const float* bq   = (const float*)d_in[9];
    const float* Wv   = (const float*)d_in[10];
    const float* bv   = (const float*)d_in[11];
    const float* Wsm  = (const float*)d_in[12];
    const float* bgat = (const float*)d_in[13];
    const float* Wsc  = (const float*)d_in[14];
    const float* bsc  = (const float*)d_in[15];

    int N = in_sizes[0] / FIN;
    int E = in_sizes[1] / 2;

    float* ws    = (float*)d_ws;
    float* h1    = ws + WS_H1;                    // N*32 floats (bf16 h1)
    float* karr  = h1 + (size_t)N * 32;           // N*16 u32
    float* srec  = karr + (size_t)N * 16;         // N*48 u32
    float* sortf = srec + (size_t)N * 48;         // E int2
    unsigned* ghist = (unsigned*)(sortf + (size_t)E * 2);
    unsigned* gcur  = ghist + NBKT_MAX;
    int2* sorted = (int2*)sortf;
    float* score = (float*)d_out;

    int nbkt = (N + (1 << BG_SH) - 1) >> BG_SH;   // 98 for N=100000
    int nE4 = E >> 2;
    int c4 = (nE4 + 255) / 256;                   // int4-chunk per sort block
    int NB = (N + 63) / 64;
    int NBE = (E + EC - 1) / EC;

    gnn_zero<<<1, 256, 0, stream>>>(ghist, nbkt);
    gnn_prep<<<14, 256, 0, stream>>>(W1, W2, b2, Wk, bk, Wq, bq, Wv, bv,
                                     Wsm, Wsc, bgat, bsc, ws);
    gnn_hist<<<256, 256, 0, stream>>>(ei, ghist, E, nbkt, c4);
    gnn_scan<<<1, 256, 0, stream>>>(ghist, gcur, nbkt);
    gnn_scatter<<<256, 256, 0, stream>>>(ei, gcur, sorted, E, nbkt, c4);
    gnn_mlp1<<<NB, 256, 0, stream>>>(x, b1, ws, (uint2*)h1, N);
    gnn_kqvs<<<NB, 256, 0, stream>>>(ws, (const uint2*)h1, (unsigned*)karr,
                                     (unsigned*)srec, score, N);
    gnn_edge_sorted<<<NBE, 256, 0, stream>>>(sorted, (const uint4*)karr,
                                             (const uint4*)srec, score, E, N);
}